// Round 9
// baseline (346.125 us; speedup 1.0000x reference)
//
#include <hip/hip_runtime.h>
#include <hip/hip_bf16.h>
#include <math.h>

// ---------------------------------------------------------------------------
// GraphSAGE (gcn aggregator) x3 layers.
// R9: XCD-pinned PLANE-sliced aggregation, verified idioms only.
//   Gather sources stored as contiguous planes [PL][N][32 feats] bf16
//   (3.2 MB/plane, dense cache lines). plane = blockIdx % PL; round-robin
//   blockIdx%8 -> XCD keeps one plane per XCD L2. Gather loop is R4's
//   verified direct-col_idx pattern (no shfl); shfl_xor butterfly reduce.
//   GEMM epilogues emit plane layout. R8's interleaved-slice + non-uniform
//   shfl gather (failed absmax) is abandoned.
// ---------------------------------------------------------------------------

#define NFEAT 128
#define BSH   7                 // bucket shift: 128 nodes per bucket
#define NBUKP 512               // padded bucket count (actual 391)
#define EPB   2048              // edges per block in partition passes
#define BCAP  3072              // max edges per bucket handled in LDS

typedef __attribute__((ext_vector_type(8))) short bf16x8;  // 8 bf16 = 4 VGPRs
typedef __attribute__((ext_vector_type(4))) float f32x4;

__device__ __forceinline__ unsigned short f2bf(float f) {  // RTNE fp32->bf16
    unsigned u = __float_as_uint(f);
    u += 0x7fffu + ((u >> 16) & 1u);
    return (unsigned short)(u >> 16);
}
__device__ __forceinline__ float bflo(unsigned u) { return __uint_as_float(u << 16); }
__device__ __forceinline__ float bfhi(unsigned u) { return __uint_as_float(u & 0xffff0000u); }

// ---- Pass A1: coarse bucket histogram -------------------------------------

__global__ __launch_bounds__(256) void partA1_count(const int* __restrict__ dst,
                                                    int* __restrict__ bucketCnt, int E) {
    __shared__ int hist[NBUKP];
    const int t = threadIdx.x;
    hist[t] = 0; hist[t + 256] = 0;
    __syncthreads();
    const int base = blockIdx.x * EPB;
#pragma unroll
    for (int j = 0; j < EPB / 256; ++j) {
        int e = base + t + 256 * j;
        if (e < E) atomicAdd(&hist[dst[e] >> BSH], 1);
    }
    __syncthreads();
    for (int b = t; b < NBUKP; b += 256) {
        int h = hist[b];
        if (h > 0) atomicAdd(&bucketCnt[b], h);
    }
}

// ---- Pass A2: scan bucket counts -> bucketOff, bucketCursor ---------------

__global__ __launch_bounds__(512) void partA2_scan(const int* __restrict__ bucketCnt,
                                                   int* __restrict__ bucketOff,
                                                   int* __restrict__ bucketCursor,
                                                   int* __restrict__ row_ptr, int N, int E) {
    __shared__ int sc[NBUKP];
    const int t = threadIdx.x;
    sc[t] = bucketCnt[t];
    __syncthreads();
    for (int off = 1; off < NBUKP; off <<= 1) {
        int v = (t >= off) ? sc[t - off] : 0;
        __syncthreads();
        sc[t] += v;
        __syncthreads();
    }
    int excl = sc[t] - bucketCnt[t];
    bucketOff[t] = excl;
    bucketCursor[t] = excl;
    if (t == 0) row_ptr[N] = E;
}

// ---- Pass A3: LDS-staged scatter of (src,dst) pairs grouped by bucket -----

__global__ __launch_bounds__(256) void partA3_scatter(const int* __restrict__ src,
                                                      const int* __restrict__ dst,
                                                      int* __restrict__ bucketCursor,
                                                      unsigned long long* __restrict__ pairs,
                                                      int E) {
    __shared__ int hist[NBUKP];
    __shared__ int sc[NBUKP];
    __shared__ int lcur[NBUKP];
    __shared__ int lbase[NBUKP];
    __shared__ unsigned long long stage[EPB];
    __shared__ int destIdx[EPB];
    __shared__ int nLocalSh;

    const int t = threadIdx.x;
    hist[t] = 0; hist[t + 256] = 0;
    lcur[t] = 0; lcur[t + 256] = 0;
    __syncthreads();

    const int base = blockIdx.x * EPB;
    int bb[EPB / 256];
    unsigned long long pr[EPB / 256];
#pragma unroll
    for (int j = 0; j < EPB / 256; ++j) {
        int e = base + t + 256 * j;
        bb[j] = -1;
        if (e < E) {
            int s = src[e], d = dst[e];
            int b = d >> BSH;
            bb[j] = b;
            pr[j] = ((unsigned long long)(unsigned)d << 32) | (unsigned)s;
            atomicAdd(&hist[b], 1);
        }
    }
    __syncthreads();
    sc[t] = hist[t]; sc[t + 256] = hist[t + 256];
    __syncthreads();
    for (int off = 1; off < NBUKP; off <<= 1) {
        int v0 = (t >= off) ? sc[t - off] : 0;
        int v1 = (t + 256 >= off) ? sc[t + 256 - off] : 0;
        __syncthreads();
        sc[t] += v0; sc[t + 256] += v1;
        __syncthreads();
    }
    if (t == 255) nLocalSh = sc[NBUKP - 1];
    sc[t] -= hist[t]; sc[t + 256] -= hist[t + 256];
    for (int b = t; b < NBUKP; b += 256) {
        int h = hist[b];
        if (h > 0) lbase[b] = atomicAdd(&bucketCursor[b], h);
    }
    __syncthreads();
#pragma unroll
    for (int j = 0; j < EPB / 256; ++j) {
        int b = bb[j];
        if (b >= 0) {
            int slot = atomicAdd(&lcur[b], 1);
            int spos = sc[b] + slot;
            stage[spos] = pr[j];
            destIdx[spos] = lbase[b] + slot;
        }
    }
    __syncthreads();
    const int nLocal = nLocalSh;
#pragma unroll
    for (int j = 0; j < EPB / 256; ++j) {
        int i = t + 256 * j;
        if (i < nLocal) pairs[destIdx[i]] = stage[i];
    }
}

// ---- Pass B: per-bucket sort by dst, emit row_ptr/deg_inv/col_idx ---------

__global__ __launch_bounds__(256) void partB_build(const unsigned long long* __restrict__ pairs,
                                                   const int* __restrict__ bucketOff,
                                                   const int* __restrict__ bucketCnt,
                                                   int* __restrict__ row_ptr,
                                                   float* __restrict__ deg_inv,
                                                   int* __restrict__ col_idx, int N) {
    __shared__ unsigned long long pairsL[BCAP];
    __shared__ int srcS[BCAP];
    __shared__ int nhist[128];
    __shared__ int npref[128];
    __shared__ int ncur[128];

    const int t = threadIdx.x;
    const int b = blockIdx.x;
    const int nodeBase = b << BSH;
    const int eBeg = bucketOff[b];
    const int eCnt = bucketCnt[b];

    if (t < 128) { nhist[t] = 0; ncur[t] = 0; }
    __syncthreads();

    if (eCnt <= BCAP) {
        for (int i = t; i < eCnt; i += 256) {
            unsigned long long p = pairs[eBeg + i];
            pairsL[i] = p;
            atomicAdd(&nhist[(int)(p >> 32) - nodeBase], 1);
        }
        __syncthreads();
        if (t < 128) npref[t] = nhist[t];
        __syncthreads();
        for (int off = 1; off < 128; off <<= 1) {
            int v = (t < 128 && t >= off) ? npref[t - off] : 0;
            __syncthreads();
            if (t < 128) npref[t] += v;
            __syncthreads();
        }
        if (t < 128) npref[t] -= nhist[t];
        if (t < 128 && nodeBase + t < N) {
            row_ptr[nodeBase + t] = eBeg + npref[t];
            deg_inv[nodeBase + t] = 1.0f / (float)(nhist[t] + 1);
        }
        __syncthreads();
        for (int i = t; i < eCnt; i += 256) {
            unsigned long long p = pairsL[i];
            int d = (int)(p >> 32) - nodeBase;
            int slot = atomicAdd(&ncur[d], 1);
            srcS[npref[d] + slot] = (int)(unsigned)p;
        }
        __syncthreads();
        for (int i = t; i < eCnt; i += 256) col_idx[eBeg + i] = srcS[i];
    } else {
        for (int i = t; i < eCnt; i += 256) {
            unsigned long long p = pairs[eBeg + i];
            atomicAdd(&nhist[(int)(p >> 32) - nodeBase], 1);
        }
        __syncthreads();
        if (t < 128) npref[t] = nhist[t];
        __syncthreads();
        for (int off = 1; off < 128; off <<= 1) {
            int v = (t < 128 && t >= off) ? npref[t - off] : 0;
            __syncthreads();
            if (t < 128) npref[t] += v;
            __syncthreads();
        }
        if (t < 128) npref[t] -= nhist[t];
        if (t < 128 && nodeBase + t < N) {
            row_ptr[nodeBase + t] = eBeg + npref[t];
            deg_inv[nodeBase + t] = 1.0f / (float)(nhist[t] + 1);
        }
        __syncthreads();
        for (int i = t; i < eCnt; i += 256) {
            unsigned long long p = pairs[eBeg + i];
            int d = (int)(p >> 32) - nodeBase;
            int slot = atomicAdd(&ncur[d], 1);
            col_idx[eBeg + npref[d] + slot] = (int)(unsigned)p;
        }
    }
}

// ---- converts -------------------------------------------------------------

// x fp32 [N][128] -> 4 planes of bf16 [N][32]
__global__ __launch_bounds__(256) void cvt_x_planes_kernel(const float* __restrict__ in,
                                                           ushort* __restrict__ outp, int N) {
    int i = blockIdx.x * blockDim.x + threadIdx.x;  // group of 4 floats
    if (i >= N * 32) return;
    int node = i >> 5;
    int f0   = (i & 31) * 4;
    int p    = f0 >> 5;
    int c    = f0 & 31;
    float4 f = *(const float4*)(in + (size_t)node * NFEAT + f0);
    *(ushort4*)(outp + ((size_t)p * N + node) * 32 + c) =
        make_ushort4(f2bf(f.x), f2bf(f.y), f2bf(f.z), f2bf(f.w));
}

__global__ __launch_bounds__(256) void cvt_weights_kernel(const float* __restrict__ W1,
                                                          const float* __restrict__ W2,
                                                          const float* __restrict__ W3,
                                                          ushort* __restrict__ w1,
                                                          ushort* __restrict__ w2,
                                                          ushort* __restrict__ w3,
                                                          int n1, int n2, int n3) {
    int i = blockIdx.x * blockDim.x + threadIdx.x;
    const float* src; ushort* dst; int off;
    if (i < n1)            { src = W1; dst = w1; off = i; }
    else if (i < n1 + n2)  { src = W2; dst = w2; off = i - n1; }
    else if (i < n1+n2+n3) { src = W3; dst = w3; off = i - n1 - n2; }
    else return;
    float4 f = *(const float4*)(src + (size_t)off * 4);
    *(ushort4*)(dst + (size_t)off * 4) = make_ushort4(f2bf(f.x), f2bf(f.y), f2bf(f.z), f2bf(f.w));
}

// ---- Plane-sliced aggregation ---------------------------------------------
// Xpl: PL planes, each [N][16] uints (32 feats). Block = 16 nodes x 1 plane,
// plane s = blockIdx % PL (XCD-pinned via %8 round-robin dispatch).
// Wave w handles nodes tile*16+w*4+i. Edge-group g (16 lanes, f=lane&15)
// processes edges e ≡ g (mod 4) with DIRECT col_idx loads (R4-verified
// pattern), 2 gather streams; shfl_xor butterfly reduces the 4 groups.
// SIG=0: g==0 lanes write bf16 slice into row-major outB [N][PL*16] uints.
// SIG=1: +bias, sigmoid, write fp32 out [N][64].

template<int PL, int SIG>
__global__ __launch_bounds__(256) void agg_plane_kernel(
        const ushort* __restrict__ Xpl,
        const int* __restrict__ row_ptr,
        const int* __restrict__ col_idx,
        const float* __restrict__ deg_inv,
        const float* __restrict__ bias,
        ushort* __restrict__ outB,
        float* __restrict__ outF, int N) {
    const int s    = blockIdx.x % PL;
    const int tile = blockIdx.x / PL;
    const int w    = threadIdx.x >> 6;
    const int lane = threadIdx.x & 63;
    const int g    = lane >> 4;
    const int f    = lane & 15;
    const unsigned* P = (const unsigned*)Xpl + (size_t)s * N * 16;

#pragma unroll
    for (int i = 0; i < 4; ++i) {
        const int v = tile * 16 + w * 4 + i;
        if (v >= N) continue;
        const int beg = row_ptr[v];
        const int end = row_ptr[v + 1];

        float a0 = 0.f, a1 = 0.f, b0 = 0.f, b1 = 0.f;
        int e = beg + g;
        for (; e + 4 < end; e += 8) {
            int s0 = col_idx[e];
            int s1 = col_idx[e + 4];
            unsigned u0 = P[(size_t)s0 * 16 + f];
            unsigned u1 = P[(size_t)s1 * 16 + f];
            a0 += bflo(u0); a1 += bfhi(u0);
            b0 += bflo(u1); b1 += bfhi(u1);
        }
        if (e < end) {
            unsigned u0 = P[(size_t)col_idx[e] * 16 + f];
            a0 += bflo(u0); a1 += bfhi(u0);
        }
        a0 += b0; a1 += b1;
        a0 += __shfl_xor(a0, 16, 64); a0 += __shfl_xor(a0, 32, 64);
        a1 += __shfl_xor(a1, 16, 64); a1 += __shfl_xor(a1, 32, 64);
        if (g == 0) {
            unsigned us = P[(size_t)v * 16 + f];
            float inv = deg_inv[v];
            float r0 = (a0 + bflo(us)) * inv;
            float r1 = (a1 + bfhi(us)) * inv;
            if (!SIG) {
                ((unsigned*)outB)[(size_t)v * (PL * 16) + s * 16 + f] =
                    (unsigned)f2bf(r0) | ((unsigned)f2bf(r1) << 16);
            } else {
                r0 += bias[s * 32 + 2 * f + 0];
                r1 += bias[s * 32 + 2 * f + 1];
                r0 = 1.0f / (1.0f + __expf(-r0));
                r1 = 1.0f / (1.0f + __expf(-r1));
                *(float2*)(outF + (size_t)v * 64 + s * 32 + 2 * f) = make_float2(r0, r1);
            }
        }
    }
}

// ---- MFMA GEMM: out = act(H[N,128](bf16) @ W[OUT,128]^T(bf16) + b) --------
// One wave = 16-row stripe, direct global frags, no LDS (verified R6).
// PLANE_OUT=1: write 32-feat planes [OUT/32][N][32] (for plane-sliced agg).
// C/D layout (verified m89/m91): col = lane&15, row = quad*4 + reg.

template<int NCT, int PLANE_OUT>
__global__ __launch_bounds__(256) void gemm_mfma_kernel(const ushort* __restrict__ Hb,
                                                        const ushort* __restrict__ Wb,
                                                        const float* __restrict__ bias,
                                                        ushort* __restrict__ outB,
                                                        int N, int relu) {
    const int OUT  = NCT * 16;
    const int wid  = blockIdx.x * 4 + (threadIdx.x >> 6);
    const int lane = threadIdx.x & 63;
    const int m    = lane & 15;
    const int quad = lane >> 4;
    const int row0 = wid * 16;
    if (row0 >= N) return;

    f32x4 acc[NCT];
#pragma unroll
    for (int i = 0; i < NCT; ++i) acc[i] = (f32x4){0.f, 0.f, 0.f, 0.f};

    const ushort* hrow = Hb + (size_t)(row0 + m) * NFEAT + quad * 8;
    const ushort* wrow = Wb + (size_t)m * NFEAT + quad * 8;

#pragma unroll
    for (int k0 = 0; k0 < NFEAT; k0 += 32) {
        bf16x8 a = *(const bf16x8*)(hrow + k0);
#pragma unroll
        for (int ct = 0; ct < NCT; ++ct) {
            bf16x8 b = *(const bf16x8*)(wrow + (size_t)ct * 16 * NFEAT + k0);
            acc[ct] = __builtin_amdgcn_mfma_f32_16x16x32_bf16(a, b, acc[ct], 0, 0, 0);
        }
    }

#pragma unroll
    for (int ct = 0; ct < NCT; ++ct) {
        float bv = bias ? bias[ct * 16 + m] : 0.f;
#pragma unroll
        for (int r = 0; r < 4; ++r) {
            float v = acc[ct][r] + bv;
            if (relu) v = fmaxf(v, 0.f);
            int row = row0 + quad * 4 + r;
            if (PLANE_OUT) {
                outB[((size_t)(ct >> 1) * N + row) * 32 + (ct & 1) * 16 + m] = f2bf(v);
            } else {
                outB[(size_t)row * OUT + ct * 16 + m] = f2bf(v);
            }
        }
    }
}

// ---- Fused GEMM2+GEMM3: g = relu(A @ W2^T + b2) @ W3^T --------------------
// Verified R7/R8 MFMA structure; phase-B epilogue writes g as 2 planes
// [2][N][32] for the plane-sliced final aggregation.

__global__ __launch_bounds__(256) void gemm23_kernel(const ushort* __restrict__ Ab,
                                                     const ushort* __restrict__ W2b,
                                                     const float* __restrict__ b2,
                                                     const ushort* __restrict__ W3b,
                                                     ushort* __restrict__ outP, int N) {
    __shared__ ushort A[16][136];
    __shared__ ushort H2[16][136];
    const int t    = threadIdx.x;
    const int w    = t >> 6;
    const int lane = t & 63;
    const int base = blockIdx.x * 16;

    // stage A tile: thread t loads 16B of row t>>4
    {
        const int r  = t >> 4;
        const int c8 = (t & 15) * 8;
        bf16x8 av = {};
        if (base + r < N) av = *(const bf16x8*)(Ab + (size_t)(base + r) * NFEAT + c8);
        *(bf16x8*)&A[r][c8] = av;
    }
    __syncthreads();

    const int m    = lane & 15;
    const int quad = lane >> 4;
    // phase A: H2 = relu(A @ W2^T + b2); wave w -> cols [32w, 32w+32)
    f32x4 acc0 = {0.f, 0.f, 0.f, 0.f};
    f32x4 acc1 = {0.f, 0.f, 0.f, 0.f};
    {
        const ushort* arow = &A[m][quad * 8];
        const ushort* wrow = W2b + (size_t)(w * 32 + m) * NFEAT + quad * 8;
#pragma unroll
        for (int k0 = 0; k0 < NFEAT; k0 += 32) {
            bf16x8 a  = *(const bf16x8*)(arow + k0);
            bf16x8 bA = *(const bf16x8*)(wrow + k0);
            bf16x8 bB = *(const bf16x8*)(wrow + 16 * NFEAT + k0);
            acc0 = __builtin_amdgcn_mfma_f32_16x16x32_bf16(a, bA, acc0, 0, 0, 0);
            acc1 = __builtin_amdgcn_mfma_f32_16x16x32_bf16(a, bB, acc1, 0, 0, 0);
        }
    }
    const float bv0 = b2[w * 32 + m];
    const float bv1 = b2[w * 32 + 16 + m];
#pragma unroll
    for (int r = 0; r < 4; ++r) {
        H2[quad * 4 + r][w * 32 + m]      = f2bf(fmaxf(acc0[r] + bv0, 0.f));
        H2[quad * 4 + r][w * 32 + 16 + m] = f2bf(fmaxf(acc1[r] + bv1, 0.f));
    }
    __syncthreads();
    // phase B: G = H2 @ W3^T; wave w -> cols [16w, 16w+16)
    f32x4 acc3 = {0.f, 0.f, 0.f, 0.f};
    const ushort* hrow  = &H2[m][quad * 8];
    const ushort* w3row = W3b + (size_t)(w * 16 + m) * NFEAT + quad * 8;
#pragma unroll
    for (int k0 = 0; k0 < NFEAT; k0 += 32) {
        bf16x8 a = *(const bf16x8*)(hrow + k0);
        bf16x8 b = *(const bf16x8*)(w3row + k0);
        acc3 = __builtin_amdgcn_mfma_f32_16x16x32_bf16(a, b, acc3, 0, 0, 0);
    }
#pragma unroll
    for (int r = 0; r < 4; ++r) {
        int row = base + quad * 4 + r;
        if (row < N)
            outP[((size_t)(w >> 1) * N + row) * 32 + (w & 1) * 16 + m] = f2bf(acc3[r]);
    }
}

// ---------------------------------------------------------------------------

static inline size_t align256(size_t x) { return (x + 255) & ~(size_t)255; }

extern "C" void kernel_launch(void* const* d_in, const int* in_sizes, int n_in,
                              void* d_out, int out_size, void* d_ws, size_t ws_size,
                              hipStream_t stream) {
    const float* x   = (const float*)d_in[0];
    const int*   src = (const int*)d_in[1];
    const int*   dst = (const int*)d_in[2];
    const float* W1  = (const float*)d_in[3];
    const float* b1  = (const float*)d_in[4];
    const float* W2  = (const float*)d_in[5];
    const float* b2  = (const float*)d_in[6];
    const float* W3  = (const float*)d_in[7];
    const float* b3  = (const float*)d_in[8];
    float*       out = (float*)d_out;

    const int N = in_sizes[0] / NFEAT;     // 50000
    const int E = in_sizes[1];             // 800000
    const int D_OUT = in_sizes[7] / NFEAT; // 64
    const int NBUK = (N + (1 << BSH) - 1) >> BSH;   // 391
    const int PBLK = (E + EPB - 1) / EPB;           // 391

    // workspace carve:
    //   xpl : x as 4 planes (12.8MB) -> reused as gpl (2 planes, 6.4MB)
    //   h1pl: h1 as 4 planes        ; pairs (CSR, 6.4MB) aliases it
    //   aggB: row-major agg output / GEMM input (12.8MB)
    char* ws = (char*)d_ws;
    int* row_ptr      = (int*)ws;  ws += align256((size_t)(N + 1) * 4);
    int* col_idx      = (int*)ws;  ws += align256((size_t)E * 4);
    float* deg_inv    = (float*)ws; ws += align256((size_t)N * 4);
    int* bucketCnt    = (int*)ws;  ws += align256((size_t)NBUKP * 4);
    int* bucketOff    = (int*)ws;  ws += align256((size_t)NBUKP * 4);
    int* bucketCursor = (int*)ws;  ws += align256((size_t)NBUKP * 4);
    ushort* w1bf      = (ushort*)ws; ws += align256((size_t)NFEAT * NFEAT * 2);
    ushort* w2bf      = (ushort*)ws; ws += align256((size_t)NFEAT * NFEAT * 2);
    ushort* w3bf      = (ushort*)ws; ws += align256((size_t)D_OUT * NFEAT * 2);
    ushort* xpl       = (ushort*)ws; ws += align256((size_t)N * NFEAT * 2);
    ushort* h1pl      = (ushort*)ws; ws += align256((size_t)N * NFEAT * 2);
    ushort* aggB      = (ushort*)ws; ws += align256((size_t)N * NFEAT * 2);
    ushort* gpl = xpl;                                      // x dead after L1 agg
    unsigned long long* pairs = (unsigned long long*)h1pl;  // dead before gemm1

    // ---- CSR build via 2-level partition ----
    hipMemsetAsync(bucketCnt, 0, (size_t)NBUKP * 4, stream);
    partA1_count<<<PBLK, 256, 0, stream>>>(dst, bucketCnt, E);
    partA2_scan<<<1, NBUKP, 0, stream>>>(bucketCnt, bucketOff, bucketCursor, row_ptr, N, E);
    partA3_scatter<<<PBLK, 256, 0, stream>>>(src, dst, bucketCursor, pairs, E);
    partB_build<<<NBUK, 256, 0, stream>>>(pairs, bucketOff, bucketCnt, row_ptr, deg_inv, col_idx, N);

    // ---- converts ----
    cvt_x_planes_kernel<<<(N * 32 + 255) / 256, 256, 0, stream>>>(x, xpl, N);
    const int n1 = NFEAT * NFEAT / 4, n2 = NFEAT * NFEAT / 4, n3 = D_OUT * NFEAT / 4;
    cvt_weights_kernel<<<(n1 + n2 + n3 + 255) / 256, 256, 0, stream>>>(
        W1, W2, W3, w1bf, w2bf, w3bf, n1, n2, n3);

    const int tiles      = (N + 15) / 16;       // 3125
    const int gemmBlocks = (N / 16 + 3) / 4;    // 782 (one wave / 16 rows)

    // layer 1: plane agg(x) -> aggB; MFMA W1+b1+relu -> h1 planes
    agg_plane_kernel<4, 0><<<tiles * 4, 256, 0, stream>>>(
        xpl, row_ptr, col_idx, deg_inv, nullptr, aggB, nullptr, N);
    gemm_mfma_kernel<8, 1><<<gemmBlocks, 256, 0, stream>>>(aggB, w1bf, b1, h1pl, N, 1);
    // layer 2 (+3a): plane agg(h1) -> aggB; fused W2+relu, W3 -> g planes
    agg_plane_kernel<4, 0><<<tiles * 4, 256, 0, stream>>>(
        h1pl, row_ptr, col_idx, deg_inv, nullptr, aggB, nullptr, N);
    gemm23_kernel<<<tiles, 256, 0, stream>>>(aggB, w2bf, b2, w3bf, gpl, N);
    // layer 3b: plane agg(g) + b3 + sigmoid -> out
    agg_plane_kernel<2, 1><<<tiles * 2, 256, 0, stream>>>(
        gpl, row_ptr, col_idx, deg_inv, b3, nullptr, out, N);
}

// Round 10
// 242.400 us; speedup vs baseline: 1.4279x; 1.4279x over previous
//
#include <hip/hip_runtime.h>
#include <hip/hip_bf16.h>
#include <math.h>

// ---------------------------------------------------------------------------
// GraphSAGE (gcn aggregator) x3 layers.
// R10: R7's verified fused structure (241 us) + SOURCE-TILED edge order.
//   partB_build sorts each node's edges by src>>13 (8 tiles x 2.1 MB bf16).
//   Gather loops walk tiles in global order -> per-XCD L2 holds ~1 tile.
//   Agg kernels unchanged from R7 (per-edge cost identical); only the CSR
//   counting-sort key widened to (node<<3)|tile (1024 bins).
//   R9 lesson: plane-splitting fixed FETCH (81->29MB) but 4x'd per-edge
//   overhead (70us, VALU 43%). This keeps R7 overhead + adds locality.
// ---------------------------------------------------------------------------

#define NFEAT 128
#define BSH   7                 // bucket shift: 128 nodes per bucket
#define NBUKP 512               // padded bucket count (actual 391)
#define EPB   2048              // edges per block in partition passes
#define BCAP  3072              // max edges per bucket handled in LDS
#define TSH   13                // src tile shift: 8 tiles of 8192 nodes

typedef __attribute__((ext_vector_type(8))) short bf16x8;  // 8 bf16 = 4 VGPRs
typedef __attribute__((ext_vector_type(4))) float f32x4;

__device__ __forceinline__ unsigned short f2bf(float f) {  // RTNE fp32->bf16
    unsigned u = __float_as_uint(f);
    u += 0x7fffu + ((u >> 16) & 1u);
    return (unsigned short)(u >> 16);
}
__device__ __forceinline__ float bflo(unsigned u) { return __uint_as_float(u << 16); }
__device__ __forceinline__ float bfhi(unsigned u) { return __uint_as_float(u & 0xffff0000u); }

// ---- Pass A1: coarse bucket histogram -------------------------------------

__global__ __launch_bounds__(256) void partA1_count(const int* __restrict__ dst,
                                                    int* __restrict__ bucketCnt, int E) {
    __shared__ int hist[NBUKP];
    const int t = threadIdx.x;
    hist[t] = 0; hist[t + 256] = 0;
    __syncthreads();
    const int base = blockIdx.x * EPB;
#pragma unroll
    for (int j = 0; j < EPB / 256; ++j) {
        int e = base + t + 256 * j;
        if (e < E) atomicAdd(&hist[dst[e] >> BSH], 1);
    }
    __syncthreads();
    for (int b = t; b < NBUKP; b += 256) {
        int h = hist[b];
        if (h > 0) atomicAdd(&bucketCnt[b], h);
    }
}

// ---- Pass A2: scan bucket counts -> bucketOff, bucketCursor ---------------

__global__ __launch_bounds__(512) void partA2_scan(const int* __restrict__ bucketCnt,
                                                   int* __restrict__ bucketOff,
                                                   int* __restrict__ bucketCursor,
                                                   int* __restrict__ row_ptr, int N, int E) {
    __shared__ int sc[NBUKP];
    const int t = threadIdx.x;
    sc[t] = bucketCnt[t];
    __syncthreads();
    for (int off = 1; off < NBUKP; off <<= 1) {
        int v = (t >= off) ? sc[t - off] : 0;
        __syncthreads();
        sc[t] += v;
        __syncthreads();
    }
    int excl = sc[t] - bucketCnt[t];
    bucketOff[t] = excl;
    bucketCursor[t] = excl;
    if (t == 0) row_ptr[N] = E;
}

// ---- Pass A3: LDS-staged scatter of (src,dst) pairs grouped by bucket -----

__global__ __launch_bounds__(256) void partA3_scatter(const int* __restrict__ src,
                                                      const int* __restrict__ dst,
                                                      int* __restrict__ bucketCursor,
                                                      unsigned long long* __restrict__ pairs,
                                                      int E) {
    __shared__ int hist[NBUKP];
    __shared__ int sc[NBUKP];
    __shared__ int lcur[NBUKP];
    __shared__ int lbase[NBUKP];
    __shared__ unsigned long long stage[EPB];
    __shared__ int destIdx[EPB];
    __shared__ int nLocalSh;

    const int t = threadIdx.x;
    hist[t] = 0; hist[t + 256] = 0;
    lcur[t] = 0; lcur[t + 256] = 0;
    __syncthreads();

    const int base = blockIdx.x * EPB;
    int bb[EPB / 256];
    unsigned long long pr[EPB / 256];
#pragma unroll
    for (int j = 0; j < EPB / 256; ++j) {
        int e = base + t + 256 * j;
        bb[j] = -1;
        if (e < E) {
            int s = src[e], d = dst[e];
            int b = d >> BSH;
            bb[j] = b;
            pr[j] = ((unsigned long long)(unsigned)d << 32) | (unsigned)s;
            atomicAdd(&hist[b], 1);
        }
    }
    __syncthreads();
    sc[t] = hist[t]; sc[t + 256] = hist[t + 256];
    __syncthreads();
    for (int off = 1; off < NBUKP; off <<= 1) {
        int v0 = (t >= off) ? sc[t - off] : 0;
        int v1 = (t + 256 >= off) ? sc[t + 256 - off] : 0;
        __syncthreads();
        sc[t] += v0; sc[t + 256] += v1;
        __syncthreads();
    }
    if (t == 255) nLocalSh = sc[NBUKP - 1];
    sc[t] -= hist[t]; sc[t + 256] -= hist[t + 256];
    for (int b = t; b < NBUKP; b += 256) {
        int h = hist[b];
        if (h > 0) lbase[b] = atomicAdd(&bucketCursor[b], h);
    }
    __syncthreads();
#pragma unroll
    for (int j = 0; j < EPB / 256; ++j) {
        int b = bb[j];
        if (b >= 0) {
            int slot = atomicAdd(&lcur[b], 1);
            int spos = sc[b] + slot;
            stage[spos] = pr[j];
            destIdx[spos] = lbase[b] + slot;
        }
    }
    __syncthreads();
    const int nLocal = nLocalSh;
#pragma unroll
    for (int j = 0; j < EPB / 256; ++j) {
        int i = t + 256 * j;
        if (i < nLocal) pairs[destIdx[i]] = stage[i];
    }
}

// ---- Pass B: per-bucket sort by (dst, srcTile), emit CSR ------------------
// Key = ((dst-nodeBase)<<3) | (src>>TSH): 1024 bins. Each node's edge list
// comes out grouped by source tile -> L2-local gathers downstream.

__global__ __launch_bounds__(256) void partB_build(const unsigned long long* __restrict__ pairs,
                                                   const int* __restrict__ bucketOff,
                                                   const int* __restrict__ bucketCnt,
                                                   int* __restrict__ row_ptr,
                                                   float* __restrict__ deg_inv,
                                                   int* __restrict__ col_idx, int N) {
    __shared__ unsigned long long pairsL[BCAP];
    __shared__ int srcS[BCAP];
    __shared__ int nhist[1024];
    __shared__ int npref[1024];
    __shared__ int ncur[1024];
    __shared__ int red[256];

    const int t = threadIdx.x;
    const int b = blockIdx.x;
    const int nodeBase = b << BSH;
    const int eBeg = bucketOff[b];
    const int eCnt = bucketCnt[b];

#pragma unroll
    for (int k = 0; k < 4; ++k) { nhist[t + 256 * k] = 0; ncur[t + 256 * k] = 0; }
    __syncthreads();

    const bool inLds = (eCnt <= BCAP);

    // histogram over 1024 (node, tile) bins
    for (int i = t; i < eCnt; i += 256) {
        unsigned long long p = pairs[eBeg + i];
        int d = (int)(p >> 32);
        int s = (int)(unsigned)p;
        if (inLds) pairsL[i] = p;
        atomicAdd(&nhist[((d - nodeBase) << 3) | (s >> TSH)], 1);
    }
    __syncthreads();

    // exclusive scan of nhist[1024]: thread t sums 4 consecutive bins,
    // 256-wide Hillis-Steele on partials, then local exclusive write-back.
    {
        const int b4 = t * 4;
        int s0 = nhist[b4], s1 = nhist[b4 + 1], s2 = nhist[b4 + 2], s3 = nhist[b4 + 3];
        red[t] = s0 + s1 + s2 + s3;
        __syncthreads();
        for (int off = 1; off < 256; off <<= 1) {
            int v = (t >= off) ? red[t - off] : 0;
            __syncthreads();
            red[t] += v;
            __syncthreads();
        }
        int run = (t == 0) ? 0 : red[t - 1];
        npref[b4] = run; run += s0;
        npref[b4 + 1] = run; run += s1;
        npref[b4 + 2] = run; run += s2;
        npref[b4 + 3] = run;
    }
    __syncthreads();

    // per-node row_ptr / deg_inv (node's list starts at its tile-0 bin)
    if (t < 128 && nodeBase + t < N) {
        int start = npref[t << 3];
        int degN;
        if (t < 127) degN = npref[(t + 1) << 3] - start;
        else {
            degN = eCnt - start;
        }
        row_ptr[nodeBase + t] = eBeg + start;
        deg_inv[nodeBase + t] = 1.0f / (float)(degN + 1);
    }
    __syncthreads();

    if (inLds) {
        for (int i = t; i < eCnt; i += 256) {
            unsigned long long p = pairsL[i];
            int d = (int)(p >> 32);
            int s = (int)(unsigned)p;
            int k = ((d - nodeBase) << 3) | (s >> TSH);
            int slot = atomicAdd(&ncur[k], 1);
            srcS[npref[k] + slot] = s;
        }
        __syncthreads();
        for (int i = t; i < eCnt; i += 256) col_idx[eBeg + i] = srcS[i];
    } else {
        for (int i = t; i < eCnt; i += 256) {
            unsigned long long p = pairs[eBeg + i];
            int d = (int)(p >> 32);
            int s = (int)(unsigned)p;
            int k = ((d - nodeBase) << 3) | (s >> TSH);
            int slot = atomicAdd(&ncur[k], 1);
            col_idx[eBeg + npref[k] + slot] = s;
        }
    }
}

// ---- fp32 -> bf16 converts ------------------------------------------------

__global__ __launch_bounds__(256) void cvt_bf16_kernel(const float* __restrict__ in,
                                                       ushort* __restrict__ outb, int n4) {
    int i = blockIdx.x * blockDim.x + threadIdx.x;
    if (i < n4) {
        float4 f = *(const float4*)(in + (size_t)i * 4);
        ushort4 u = make_ushort4(f2bf(f.x), f2bf(f.y), f2bf(f.z), f2bf(f.w));
        *(ushort4*)(outb + (size_t)i * 4) = u;
    }
}

__global__ __launch_bounds__(256) void cvt_weights_kernel(const float* __restrict__ W1,
                                                          const float* __restrict__ W2,
                                                          const float* __restrict__ W3,
                                                          ushort* __restrict__ w1,
                                                          ushort* __restrict__ w2,
                                                          ushort* __restrict__ w3,
                                                          int n1, int n2, int n3) {
    int i = blockIdx.x * blockDim.x + threadIdx.x;
    const float* src; ushort* dst; int off;
    if (i < n1)            { src = W1; dst = w1; off = i; }
    else if (i < n1 + n2)  { src = W2; dst = w2; off = i - n1; }
    else if (i < n1+n2+n3) { src = W3; dst = w3; off = i - n1 - n2; }
    else return;
    float4 f = *(const float4*)(src + (size_t)off * 4);
    *(ushort4*)(dst + (size_t)off * 4) = make_ushort4(f2bf(f.x), f2bf(f.y), f2bf(f.z), f2bf(f.w));
}

// ---- Fused: 16-node agg -> LDS -> MFMA GEMM(s) (verified R7) --------------

template<int SECOND>
__global__ __launch_bounds__(256) void fused_agg_gemm_kernel(
        const ushort* __restrict__ Xb,
        const int* __restrict__ row_ptr,
        const int* __restrict__ col_idx,
        const float* __restrict__ deg_inv,
        const ushort* __restrict__ Wb,     // [128,128] bf16
        const float* __restrict__ bias,    // [128]
        const ushort* __restrict__ W3b,    // [64,128] bf16 (SECOND only)
        ushort* __restrict__ outB, int N) {
    __shared__ ushort A[16][136];                    // +8 pad
    __shared__ ushort H2[SECOND ? 16 : 1][136];

    const int t    = threadIdx.x;
    const int w    = t >> 6;
    const int lane = t & 63;
    const int base = blockIdx.x * 16;
    const unsigned* Xu = (const unsigned*)Xb;        // row stride 64 uints

    // ---- phase 1: aggregate 4 nodes per wave into LDS ----
#pragma unroll
    for (int i = 0; i < 4; ++i) {
        const int v = base + w * 4 + i;
        if (v < N) {
            const int beg = row_ptr[v];
            const int end = row_ptr[v + 1];
            const int deg = end - beg;
            int cidx = 0;
            if (lane < deg) cidx = col_idx[beg + lane];

            float a0 = 0.f, a1 = 0.f, b0 = 0.f, b1 = 0.f;
            float c0 = 0.f, c1 = 0.f, d0 = 0.f, d1 = 0.f;
            const int nfast = deg < 64 ? deg : 64;
            int j = 0;
            for (; j + 3 < nfast; j += 4) {
                int s0 = __shfl(cidx, j + 0, 64);
                int s1 = __shfl(cidx, j + 1, 64);
                int s2 = __shfl(cidx, j + 2, 64);
                int s3 = __shfl(cidx, j + 3, 64);
                unsigned u0 = Xu[(size_t)s0 * 64 + lane];
                unsigned u1 = Xu[(size_t)s1 * 64 + lane];
                unsigned u2 = Xu[(size_t)s2 * 64 + lane];
                unsigned u3 = Xu[(size_t)s3 * 64 + lane];
                a0 += bflo(u0); a1 += bfhi(u0);
                b0 += bflo(u1); b1 += bfhi(u1);
                c0 += bflo(u2); c1 += bfhi(u2);
                d0 += bflo(u3); d1 += bfhi(u3);
            }
            for (; j < nfast; ++j) {
                int s0 = __shfl(cidx, j, 64);
                unsigned u0 = Xu[(size_t)s0 * 64 + lane];
                a0 += bflo(u0); a1 += bfhi(u0);
            }
            for (int e = beg + 64; e < end; ++e) {   // rare: deg > 64
                unsigned u0 = Xu[(size_t)col_idx[e] * 64 + lane];
                a0 += bflo(u0); a1 += bfhi(u0);
            }
            unsigned us = Xu[(size_t)v * 64 + lane];
            float inv = deg_inv[v];
            float r0 = (a0 + b0 + c0 + d0 + bflo(us)) * inv;
            float r1 = (a1 + b1 + c1 + d1 + bfhi(us)) * inv;
            unsigned ru = (unsigned)f2bf(r0) | ((unsigned)f2bf(r1) << 16);
            ((unsigned*)&A[w * 4 + i][0])[lane] = ru;
        }
    }
    __syncthreads();

    // ---- phase 2: relu(A @ W^T + b), wave w -> cols [32w, 32w+32) ----
    const int m    = lane & 15;
    const int quad = lane >> 4;
    f32x4 acc0 = {0.f, 0.f, 0.f, 0.f};
    f32x4 acc1 = {0.f, 0.f, 0.f, 0.f};
    {
        const ushort* arow = &A[m][quad * 8];
        const ushort* wrow = Wb + (size_t)(w * 32 + m) * NFEAT + quad * 8;
#pragma unroll
        for (int k0 = 0; k0 < NFEAT; k0 += 32) {
            bf16x8 a  = *(const bf16x8*)(arow + k0);
            bf16x8 bA = *(const bf16x8*)(wrow + k0);
            bf16x8 bB = *(const bf16x8*)(wrow + 16 * NFEAT + k0);
            acc0 = __builtin_amdgcn_mfma_f32_16x16x32_bf16(a, bA, acc0, 0, 0, 0);
            acc1 = __builtin_amdgcn_mfma_f32_16x16x32_bf16(a, bB, acc1, 0, 0, 0);
        }
    }
    const float bv0 = bias[w * 32 + m];
    const float bv1 = bias[w * 32 + 16 + m];

    if (!SECOND) {
#pragma unroll
        for (int r = 0; r < 4; ++r) {
            int row = base + quad * 4 + r;
            if (row < N) {
                outB[(size_t)row * NFEAT + w * 32 + m]      = f2bf(fmaxf(acc0[r] + bv0, 0.f));
                outB[(size_t)row * NFEAT + w * 32 + 16 + m] = f2bf(fmaxf(acc1[r] + bv1, 0.f));
            }
        }
    } else {
#pragma unroll
        for (int r = 0; r < 4; ++r) {
            H2[quad * 4 + r][w * 32 + m]      = f2bf(fmaxf(acc0[r] + bv0, 0.f));
            H2[quad * 4 + r][w * 32 + 16 + m] = f2bf(fmaxf(acc1[r] + bv1, 0.f));
        }
        __syncthreads();
        // ---- phase 3: G = H2 @ W3^T, wave w -> cols [16w, 16w+16) ----
        f32x4 acc3 = {0.f, 0.f, 0.f, 0.f};
        const ushort* hrow  = &H2[m][quad * 8];
        const ushort* w3row = W3b + (size_t)(w * 16 + m) * NFEAT + quad * 8;
#pragma unroll
        for (int k0 = 0; k0 < NFEAT; k0 += 32) {
            bf16x8 a = *(const bf16x8*)(hrow + k0);
            bf16x8 b = *(const bf16x8*)(w3row + k0);
            acc3 = __builtin_amdgcn_mfma_f32_16x16x32_bf16(a, b, acc3, 0, 0, 0);
        }
#pragma unroll
        for (int r = 0; r < 4; ++r) {
            int row = base + quad * 4 + r;
            if (row < N) outB[(size_t)row * 64 + w * 16 + m] = f2bf(acc3[r]);
        }
    }
}

// ---- Final aggregation (64 feats, bf16) + bias + sigmoid (verified R5) ----

__global__ __launch_bounds__(256) void agg64_sigmoid_kernel(const ushort* __restrict__ Gb,
                                                            const int* __restrict__ row_ptr,
                                                            const int* __restrict__ col_idx,
                                                            const float* __restrict__ deg_inv,
                                                            const float* __restrict__ bias,
                                                            float* __restrict__ out, int N) {
    const int wp   = blockIdx.x * (blockDim.x >> 6) + (threadIdx.x >> 6);
    const int lane = threadIdx.x & 63;
    const int half = lane >> 5;
    const int hl   = lane & 31;
    const int v    = wp * 2 + half;
    const bool act = (v < N);

    int beg = 0, end = 0;
    if (act) { beg = row_ptr[v]; end = row_ptr[v + 1]; }
    const int deg = end - beg;
    const unsigned* Gu = (const unsigned*)Gb;  // row stride 32 uints

    int cidx = 0;
    if (hl < deg) cidx = col_idx[beg + hl];

    float a0 = 0.f, a1 = 0.f, b0 = 0.f, b1 = 0.f;
    float c0 = 0.f, c1 = 0.f, d0 = 0.f, d1 = 0.f;
    const int nfast = deg < 32 ? deg : 32;
    int j = 0;
    for (; j + 3 < nfast; j += 4) {
        int s0 = __shfl(cidx, j + 0, 32);
        int s1 = __shfl(cidx, j + 1, 32);
        int s2 = __shfl(cidx, j + 2, 32);
        int s3 = __shfl(cidx, j + 3, 32);
        unsigned u0 = Gu[(size_t)s0 * 32 + hl];
        unsigned u1 = Gu[(size_t)s1 * 32 + hl];
        unsigned u2 = Gu[(size_t)s2 * 32 + hl];
        unsigned u3 = Gu[(size_t)s3 * 32 + hl];
        a0 += bflo(u0); a1 += bfhi(u0);
        b0 += bflo(u1); b1 += bfhi(u1);
        c0 += bflo(u2); c1 += bfhi(u2);
        d0 += bflo(u3); d1 += bfhi(u3);
    }
    for (; j < nfast; ++j) {
        int s0 = __shfl(cidx, j, 32);
        unsigned u0 = Gu[(size_t)s0 * 32 + hl];
        a0 += bflo(u0); a1 += bfhi(u0);
    }
    for (int e = beg + 32; e < end; ++e) {
        unsigned u0 = Gu[(size_t)col_idx[e] * 32 + hl];
        a0 += bflo(u0); a1 += bfhi(u0);
    }
    if (act) {
        unsigned us = Gu[(size_t)v * 32 + hl];
        float inv = deg_inv[v];
        float r0 = (a0 + b0 + c0 + d0 + bflo(us)) * inv + bias[hl * 2 + 0];
        float r1 = (a1 + b1 + c1 + d1 + bfhi(us)) * inv + bias[hl * 2 + 1];
        r0 = 1.0f / (1.0f + __expf(-r0));
        r1 = 1.0f / (1.0f + __expf(-r1));
        *(float2*)(out + (size_t)v * 64 + hl * 2) = make_float2(r0, r1);
    }
}

// ---------------------------------------------------------------------------

static inline size_t align256(size_t x) { return (x + 255) & ~(size_t)255; }

extern "C" void kernel_launch(void* const* d_in, const int* in_sizes, int n_in,
                              void* d_out, int out_size, void* d_ws, size_t ws_size,
                              hipStream_t stream) {
    const float* x   = (const float*)d_in[0];
    const int*   src = (const int*)d_in[1];
    const int*   dst = (const int*)d_in[2];
    const float* W1  = (const float*)d_in[3];
    const float* b1  = (const float*)d_in[4];
    const float* W2  = (const float*)d_in[5];
    const float* b2  = (const float*)d_in[6];
    const float* W3  = (const float*)d_in[7];
    const float* b3  = (const float*)d_in[8];
    float*       out = (float*)d_out;

    const int N = in_sizes[0] / NFEAT;     // 50000
    const int E = in_sizes[1];             // 800000
    const int D_OUT = in_sizes[7] / NFEAT; // 64
    const int NBUK = (N + (1 << BSH) - 1) >> BSH;   // 391
    const int PBLK = (E + EPB - 1) / EPB;           // 391

    // workspace carve:
    char* ws = (char*)d_ws;
    int* row_ptr      = (int*)ws;  ws += align256((size_t)(N + 1) * 4);
    int* col_idx      = (int*)ws;  ws += align256((size_t)E * 4);
    float* deg_inv    = (float*)ws; ws += align256((size_t)N * 4);
    int* bucketCnt    = (int*)ws;  ws += align256((size_t)NBUKP * 4);
    int* bucketOff    = (int*)ws;  ws += align256((size_t)NBUKP * 4);
    int* bucketCursor = (int*)ws;  ws += align256((size_t)NBUKP * 4);
    ushort* w1bf      = (ushort*)ws; ws += align256((size_t)NFEAT * NFEAT * 2);
    ushort* w2bf      = (ushort*)ws; ws += align256((size_t)NFEAT * NFEAT * 2);
    ushort* w3bf      = (ushort*)ws; ws += align256((size_t)D_OUT * NFEAT * 2);
    ushort* xbf       = (ushort*)ws; ws += align256((size_t)N * NFEAT * 2);
    ushort* h1bf      = (ushort*)ws; ws += align256((size_t)N * NFEAT * 2);
    ushort* gbf = xbf;                                      // x dead after fused<0>
    unsigned long long* pairs = (unsigned long long*)h1bf;  // dead before fused<0>

    // ---- CSR build via 2-level partition (tile-sorted edge lists) ----
    hipMemsetAsync(bucketCnt, 0, (size_t)NBUKP * 4, stream);
    partA1_count<<<PBLK, 256, 0, stream>>>(dst, bucketCnt, E);
    partA2_scan<<<1, NBUKP, 0, stream>>>(bucketCnt, bucketOff, bucketCursor, row_ptr, N, E);
    partA3_scatter<<<PBLK, 256, 0, stream>>>(src, dst, bucketCursor, pairs, E);
    partB_build<<<NBUK, 256, 0, stream>>>(pairs, bucketOff, bucketCnt, row_ptr, deg_inv, col_idx, N);

    // ---- convert x and weights to bf16 ----
    const int n4 = N * NFEAT / 4;
    cvt_bf16_kernel<<<(n4 + 255) / 256, 256, 0, stream>>>(x, xbf, n4);
    const int n1 = NFEAT * NFEAT / 4, n2 = NFEAT * NFEAT / 4, n3 = D_OUT * NFEAT / 4;
    cvt_weights_kernel<<<(n1 + n2 + n3 + 255) / 256, 256, 0, stream>>>(
        W1, W2, W3, w1bf, w2bf, w3bf, n1, n2, n3);

    const int fusedBlocks = (N + 15) / 16;   // 3125
    const int agg64Blocks = (N + 7) / 8;     // 2 nodes/wave

    // layer 1: agg(x) -> MFMA W1 + b1 + relu -> h1bf
    fused_agg_gemm_kernel<0><<<fusedBlocks, 256, 0, stream>>>(
        xbf, row_ptr, col_idx, deg_inv, w1bf, b1, nullptr, h1bf, N);
    // layers 2+3a: agg(h1) -> MFMA W2 + b2 + relu -> MFMA W3 -> gbf
    fused_agg_gemm_kernel<1><<<fusedBlocks, 256, 0, stream>>>(
        h1bf, row_ptr, col_idx, deg_inv, w2bf, b2, w3bf, gbf, N);
    // layer 3b: aggregate g + b3 + sigmoid -> out
    agg64_sigmoid_kernel<<<agg64Blocks, 256, 0, stream>>>(gbf, row_ptr, col_idx, deg_inv, b3, out, N);
}